// Round 1
// baseline (158.529 us; speedup 1.0000x reference)
//
#include <hip/hip_runtime.h>

#define H_DIM 16
#define D_DIM 64
#define QBLK 64
#define KVBLK 64
#define NTHREADS 256

typedef __bf16 bf16x8 __attribute__((ext_vector_type(8)));
typedef float  f32x4  __attribute__((ext_vector_type(4)));

__global__ __launch_bounds__(NTHREADS, 4)
void attn_fwd(const float* __restrict__ qg, const float* __restrict__ kg,
              const float* __restrict__ vg, const int* __restrict__ cu,
              float* __restrict__ out, int nseq, int tiles)
{
    __shared__ __align__(16) __bf16 Klds[KVBLK * D_DIM]; // row-major, 16B-slot XOR swizzle
    __shared__ __align__(16) __bf16 Vlds[KVBLK * D_DIM]; // PV B-fragment order

    // XCD-bijective swizzle: all q-tiles/heads of one sequence on one XCD (L2 reuse)
    int nwg = gridDim.x;
    int bid = blockIdx.x;
    int lg = ((nwg & 7) == 0) ? ((bid & 7) * (nwg >> 3) + (bid >> 3)) : bid;

    int qt  = lg % tiles;
    int sh  = lg / tiles;
    int h   = sh % H_DIM;
    int seq = sh / H_DIM;

    int cu0 = cu[seq], cu1 = cu[seq + 1];
    int len = cu1 - cu0;
    int q0  = qt * QBLK;
    if (len <= 0 || q0 >= len) return;

    int tid  = threadIdx.x;
    int wid  = tid >> 6;
    int lane = tid & 63;
    int g    = lane >> 4;   // 16-lane group
    int c    = lane & 15;   // col-in-16

    const float SC = 0.125f * 1.44269504088896340736f; // 1/sqrt(D) * log2(e)

    // Q fragments (B operand of swapped QK^T): lane holds Q[q0+wid*16+c][32*ks + 8*g + i]
    bf16x8 qf[2];
    {
        int qrow = q0 + wid * 16 + c;
        bool valid = qrow < len;
        const float* qp = qg + (((cu0 + qrow) * H_DIM + h) * D_DIM);
        #pragma unroll
        for (int ks = 0; ks < 2; ++ks) {
            float4 a = valid ? *(const float4*)(qp + ks * 32 + g * 8)     : make_float4(0,0,0,0);
            float4 b = valid ? *(const float4*)(qp + ks * 32 + g * 8 + 4) : make_float4(0,0,0,0);
            qf[ks][0] = (__bf16)(a.x * SC); qf[ks][1] = (__bf16)(a.y * SC);
            qf[ks][2] = (__bf16)(a.z * SC); qf[ks][3] = (__bf16)(a.w * SC);
            qf[ks][4] = (__bf16)(b.x * SC); qf[ks][5] = (__bf16)(b.y * SC);
            qf[ks][6] = (__bf16)(b.z * SC); qf[ks][7] = (__bf16)(b.w * SC);
        }
    }

    f32x4 o[4] = {};
    float m_i = -3.0e38f;
    float l_i = 0.0f;

    // staging constants
    int krow = tid >> 2;       // K row
    int kcb  = tid & 3;        // 16-float column block
    int vmg  = tid >> 5;       // M*4+g group for V fragment staging
    int vd0  = (2 * tid) & 63; // two d columns per thread

    int nkv = (len + KVBLK - 1) / KVBLK;
    for (int kt = 0; kt < nkv; ++kt) {
        int kbase = kt * KVBLK;
        __syncthreads(); // protect previous iter's LDS reads

        // ---- stage K tile (rows kbase..+63), XOR-swizzled row-major
        {
            int kvr = kbase + krow;
            bool valid = kvr < len;
            const float* kp = kg + (((cu0 + kvr) * H_DIM + h) * D_DIM + kcb * 16);
            float4 f0 = valid ? *(const float4*)(kp + 0)  : make_float4(0,0,0,0);
            float4 f1 = valid ? *(const float4*)(kp + 4)  : make_float4(0,0,0,0);
            float4 f2 = valid ? *(const float4*)(kp + 8)  : make_float4(0,0,0,0);
            float4 f3 = valid ? *(const float4*)(kp + 12) : make_float4(0,0,0,0);
            bf16x8 lo, hi;
            lo[0]=(__bf16)f0.x; lo[1]=(__bf16)f0.y; lo[2]=(__bf16)f0.z; lo[3]=(__bf16)f0.w;
            lo[4]=(__bf16)f1.x; lo[5]=(__bf16)f1.y; lo[6]=(__bf16)f1.z; lo[7]=(__bf16)f1.w;
            hi[0]=(__bf16)f2.x; hi[1]=(__bf16)f2.y; hi[2]=(__bf16)f2.z; hi[3]=(__bf16)f2.w;
            hi[4]=(__bf16)f3.x; hi[5]=(__bf16)f3.y; hi[6]=(__bf16)f3.z; hi[7]=(__bf16)f3.w;
            int swz = (krow & 7) << 4;
            char* base = (char*)Klds + krow * 128;
            *(bf16x8*)(base + ((kcb * 32)      ^ swz)) = lo;
            *(bf16x8*)(base + ((kcb * 32 + 16) ^ swz)) = hi;
        }
        // ---- stage V tile in PV-fragment order: frag[(M*4+g)*64+d][i] = V[32M+16(i>>2)+4g+(i&3)][d]
        {
            bf16x8 fa, fb;
            #pragma unroll
            for (int i = 0; i < 8; ++i) {
                int kvr = kbase + ((vmg >> 2) * 32) + ((i >> 2) * 16) + ((vmg & 3) * 4) + (i & 3);
                bool valid = kvr < len;
                const float* vp = vg + (((cu0 + kvr) * H_DIM + h) * D_DIM + vd0);
                float2 f = valid ? *(const float2*)vp : make_float2(0.f, 0.f);
                fa[i] = (__bf16)f.x;
                fb[i] = (__bf16)f.y;
            }
            *(bf16x8*)(Vlds + tid * 16)     = fa;
            *(bf16x8*)(Vlds + tid * 16 + 8) = fb;
        }
        __syncthreads();

        // ---- S^T = K·Q^T : D[kv][q], lane holds col q=c, rows kv=16b+4g+r
        f32x4 sc[4] = {};
        #pragma unroll
        for (int b = 0; b < 4; ++b) {
            int rowk = 16 * b + c;
            int swz = (rowk & 7) << 4;
            const char* base = (const char*)Klds + rowk * 128;
            bf16x8 a0 = *(const bf16x8*)(base + ((16 * g)      ^ swz));
            bf16x8 a1 = *(const bf16x8*)(base + ((64 + 16 * g) ^ swz));
            sc[b] = __builtin_amdgcn_mfma_f32_16x16x32_bf16(a0, qf[0], sc[b], 0, 0, 0);
            sc[b] = __builtin_amdgcn_mfma_f32_16x16x32_bf16(a1, qf[1], sc[b], 0, 0, 0);
        }

        // ---- varlen tail mask
        if (kbase + KVBLK > len) {
            #pragma unroll
            for (int b = 0; b < 4; ++b)
                #pragma unroll
                for (int r = 0; r < 4; ++r)
                    if (kbase + 16 * b + 4 * g + r >= len) sc[b][r] = -3.0e38f;
        }

        // ---- online softmax in log2 domain (stats per q-row = c)
        float tmax = sc[0][0];
        #pragma unroll
        for (int b = 0; b < 4; ++b)
            #pragma unroll
            for (int r = 0; r < 4; ++r) tmax = fmaxf(tmax, sc[b][r]);
        tmax = fmaxf(tmax, __shfl_xor(tmax, 16));
        tmax = fmaxf(tmax, __shfl_xor(tmax, 32));
        float mnew  = fmaxf(m_i, tmax);
        float alpha = exp2f(m_i - mnew);
        m_i = mnew;

        float p[4][4];
        float psum = 0.f;
        #pragma unroll
        for (int b = 0; b < 4; ++b)
            #pragma unroll
            for (int r = 0; r < 4; ++r) {
                float e = exp2f(sc[b][r] - mnew);
                p[b][r] = e;
                psum += e;
            }
        psum += __shfl_xor(psum, 16);
        psum += __shfl_xor(psum, 32);
        l_i = l_i * alpha + psum;

        // rescale O (lane's O rows are q = 4g+r; alpha lives in lane c==q)
        float af[4];
        #pragma unroll
        for (int r = 0; r < 4; ++r) af[r] = __shfl(alpha, 4 * g + r);
        #pragma unroll
        for (int nb = 0; nb < 4; ++nb)
            #pragma unroll
            for (int r = 0; r < 4; ++r) o[nb][r] *= af[r];

        // P fragments: pos i <-> kv = 32M + 16(i>>2) + 4g + (i&3)  (same map as V staging)
        bf16x8 pf[2];
        #pragma unroll
        for (int M = 0; M < 2; ++M)
            #pragma unroll
            for (int i = 0; i < 8; ++i)
                pf[M][i] = (__bf16)p[2 * M + (i >> 2)][i & 3];

        // ---- PV: O[q][d] += P·V
        #pragma unroll
        for (int nb = 0; nb < 4; ++nb) {
            #pragma unroll
            for (int M = 0; M < 2; ++M) {
                bf16x8 vf = *(const bf16x8*)(Vlds + ((M * 4 + g) * 64 + nb * 16 + c) * 8);
                o[nb] = __builtin_amdgcn_mfma_f32_16x16x32_bf16(pf[M], vf, o[nb], 0, 0, 0);
            }
        }
    }

    // ---- epilogue: divide by row sum, store
    float linv[4];
    #pragma unroll
    for (int r = 0; r < 4; ++r) {
        float lr = __shfl(l_i, 4 * g + r);
        linv[r] = (lr > 0.f) ? 1.0f / lr : 0.f;
    }
    #pragma unroll
    for (int r = 0; r < 4; ++r) {
        int qrow = q0 + wid * 16 + 4 * g + r;
        if (qrow < len) {
            float* op = out + (((cu0 + qrow) * H_DIM + h) * D_DIM);
            #pragma unroll
            for (int nb = 0; nb < 4; ++nb)
                op[nb * 16 + c] = o[nb][r] * linv[r];
        }
    }
}

extern "C" void kernel_launch(void* const* d_in, const int* in_sizes, int n_in,
                              void* d_out, int out_size, void* d_ws, size_t ws_size,
                              hipStream_t stream) {
    const float* q  = (const float*)d_in[0];
    const float* k  = (const float*)d_in[1];
    const float* v  = (const float*)d_in[2];
    const int*   cu = (const int*)d_in[3];

    int nseq  = in_sizes[3] - 1;
    int T     = in_sizes[0] / (H_DIM * D_DIM);
    int S     = T / nseq;
    int tiles = (S + QBLK - 1) / QBLK;
    int nwg   = nseq * H_DIM * tiles;

    attn_fwd<<<nwg, NTHREADS, 0, stream>>>(q, k, v, cu, (float*)d_out, nseq, tiles);
}

// Round 2
// 87.857 us; speedup vs baseline: 1.8044x; 1.8044x over previous
//
#include <hip/hip_runtime.h>

#define H_DIM 16
#define D_DIM 64
#define QBLK 128
#define KVBLK 64
#define NTHREADS 512

typedef __bf16 bf16x8 __attribute__((ext_vector_type(8)));
typedef float  f32x4  __attribute__((ext_vector_type(4)));

__global__ __launch_bounds__(NTHREADS, 6)
void attn_fwd(const float* __restrict__ qg, const float* __restrict__ kg,
              const float* __restrict__ vg, const int* __restrict__ cu,
              float* __restrict__ out, int tiles)
{
    // double-buffered K (XOR-swizzled row-major) and V (PV-fragment order)
    __shared__ __align__(16) __bf16 Klds[2][KVBLK * D_DIM];
    __shared__ __align__(16) __bf16 Vlds[2][KVBLK * D_DIM];

    // XCD-bijective swizzle: all q-tiles/heads of one sequence on one XCD (L2 reuse)
    int nwg = gridDim.x;
    int bid = blockIdx.x;
    int lg = ((nwg & 7) == 0) ? ((bid & 7) * (nwg >> 3) + (bid >> 3)) : bid;

    int qt  = lg % tiles;
    int sh  = lg / tiles;
    int h   = sh % H_DIM;
    int seq = sh / H_DIM;

    int cu0 = cu[seq], cu1 = cu[seq + 1];
    int len = cu1 - cu0;
    int q0  = qt * QBLK;
    if (len <= 0 || q0 >= len) return;

    int tid  = threadIdx.x;
    int wid  = tid >> 6;    // 8 waves, each owns 16 q-rows
    int lane = tid & 63;
    int g    = lane >> 4;
    int c    = lane & 15;

    const float SC = 0.125f * 1.44269504088896340736f; // 1/sqrt(D) * log2(e)

    // Q fragments (B operand of swapped QK^T): lane holds Q[q0+wid*16+c][32*ks + 8*g + i]
    bf16x8 qf[2];
    {
        int qrow = q0 + wid * 16 + c;
        bool valid = qrow < len;
        const float* qp = qg + (((cu0 + qrow) * H_DIM + h) * D_DIM);
        #pragma unroll
        for (int ks = 0; ks < 2; ++ks) {
            float4 a = valid ? *(const float4*)(qp + ks * 32 + g * 8)     : make_float4(0,0,0,0);
            float4 b = valid ? *(const float4*)(qp + ks * 32 + g * 8 + 4) : make_float4(0,0,0,0);
            qf[ks][0] = (__bf16)(a.x * SC); qf[ks][1] = (__bf16)(a.y * SC);
            qf[ks][2] = (__bf16)(a.z * SC); qf[ks][3] = (__bf16)(a.w * SC);
            qf[ks][4] = (__bf16)(b.x * SC); qf[ks][5] = (__bf16)(b.y * SC);
            qf[ks][6] = (__bf16)(b.z * SC); qf[ks][7] = (__bf16)(b.w * SC);
        }
    }

    f32x4 o[4] = {};
    float m_i = -3.0e38f;
    float l_i = 0.0f;

    // staging roles (512 threads)
    int krow = tid >> 3;                       // K row 0..63
    int kc   = tid & 7;                        // 8-float col block
    int kwoff = krow * 128 + ((kc * 16) ^ ((krow & 7) << 4)); // swizzled K write byte
    int vf_  = tid >> 6;                       // V frag group f = M*4+g'
    int vd   = tid & 63;                       // V column d
    int vr0  = 32 * (vf_ >> 2) + 4 * (vf_ & 3);

    int nkv = (len + KVBLK - 1) / KVBLK;

    float4 ka, kb;
    float  vv[8];

    auto load_tile = [&](int kb0) {
        int kvr = kb0 + krow;
        if (kvr < len) {
            const float* kp = kg + (((cu0 + kvr) << 10) + (h << 6) + kc * 8);
            ka = *(const float4*)kp;
            kb = *(const float4*)(kp + 4);
        } else {
            ka = make_float4(0,0,0,0); kb = make_float4(0,0,0,0);
        }
        #pragma unroll
        for (int i = 0; i < 8; ++i) {
            int kvr2 = kb0 + vr0 + 16 * (i >> 2) + (i & 3);
            vv[i] = (kvr2 < len) ? vg[((cu0 + kvr2) << 10) + (h << 6) + vd] : 0.f;
        }
    };
    auto write_tile = [&](int buf) {
        bf16x8 kw;
        kw[0]=(__bf16)ka.x; kw[1]=(__bf16)ka.y; kw[2]=(__bf16)ka.z; kw[3]=(__bf16)ka.w;
        kw[4]=(__bf16)kb.x; kw[5]=(__bf16)kb.y; kw[6]=(__bf16)kb.z; kw[7]=(__bf16)kb.w;
        *(bf16x8*)((char*)Klds[buf] + kwoff) = kw;
        bf16x8 vw;
        #pragma unroll
        for (int i = 0; i < 8; ++i) vw[i] = (__bf16)vv[i];
        *(bf16x8*)(Vlds[buf] + (tid << 3)) = vw;   // lane-consecutive 16B: conflict-free
    };

    // prologue: stage tile 0
    load_tile(0);
    write_tile(0);
    __syncthreads();

    int cur = 0;
    for (int kt = 0; kt < nkv; ++kt) {
        int kbase = kt * KVBLK;
        bool more = (kt + 1 < nkv);
        if (more) load_tile(kbase + KVBLK);   // issue early: hides under compute

        // ---- S^T = K·Q^T : lane holds col q=c, rows kv=16b+4g+r
        f32x4 sc[4] = {};
        const __bf16* K = Klds[cur];
        __builtin_amdgcn_s_setprio(1);
        #pragma unroll
        for (int b = 0; b < 4; ++b) {
            int rowk = 16 * b + c;
            int swz = (rowk & 7) << 4;
            const char* base = (const char*)K + rowk * 128;
            bf16x8 a0 = *(const bf16x8*)(base + ((16 * g)      ^ swz));
            bf16x8 a1 = *(const bf16x8*)(base + ((64 + 16 * g) ^ swz));
            sc[b] = __builtin_amdgcn_mfma_f32_16x16x32_bf16(a0, qf[0], sc[b], 0, 0, 0);
            sc[b] = __builtin_amdgcn_mfma_f32_16x16x32_bf16(a1, qf[1], sc[b], 0, 0, 0);
        }
        __builtin_amdgcn_s_setprio(0);

        // varlen tail mask
        if (kbase + KVBLK > len) {
            #pragma unroll
            for (int b = 0; b < 4; ++b)
                #pragma unroll
                for (int r = 0; r < 4; ++r)
                    if (kbase + 16 * b + 4 * g + r >= len) sc[b][r] = -3.0e38f;
        }

        // ---- online softmax (log2 domain), tree reductions
        float b0 = fmaxf(fmaxf(sc[0][0], sc[0][1]), fmaxf(sc[0][2], sc[0][3]));
        float b1 = fmaxf(fmaxf(sc[1][0], sc[1][1]), fmaxf(sc[1][2], sc[1][3]));
        float b2 = fmaxf(fmaxf(sc[2][0], sc[2][1]), fmaxf(sc[2][2], sc[2][3]));
        float b3 = fmaxf(fmaxf(sc[3][0], sc[3][1]), fmaxf(sc[3][2], sc[3][3]));
        float tmax = fmaxf(fmaxf(b0, b1), fmaxf(b2, b3));
        tmax = fmaxf(tmax, __shfl_xor(tmax, 16));
        tmax = fmaxf(tmax, __shfl_xor(tmax, 32));
        float mnew  = fmaxf(m_i, tmax);
        float alpha = __builtin_amdgcn_exp2f(m_i - mnew);
        m_i = mnew;

        // exp directly into PV A-fragments: pos i <-> kv = 32M + 16(i>>2) + 4g + (i&3)
        bf16x8 pf[2];
        float ps0 = 0.f, ps1 = 0.f, ps2 = 0.f, ps3 = 0.f;
        #pragma unroll
        for (int M = 0; M < 2; ++M) {
            #pragma unroll
            for (int i = 0; i < 8; ++i) {
                float e = __builtin_amdgcn_exp2f(sc[2 * M + (i >> 2)][i & 3] - mnew);
                pf[M][i] = (__bf16)e;
                if ((i & 3) == 0) ps0 += e;
                else if ((i & 3) == 1) ps1 += e;
                else if ((i & 3) == 2) ps2 += e;
                else ps3 += e;
            }
        }
        float psum = (ps0 + ps1) + (ps2 + ps3);
        psum += __shfl_xor(psum, 16);
        psum += __shfl_xor(psum, 32);
        l_i = l_i * alpha + psum;

        // rescale O (lane's O rows are q = 4g+r; alpha lives in lane c==q)
        float af[4];
        #pragma unroll
        for (int r = 0; r < 4; ++r) af[r] = __shfl(alpha, 4 * g + r);
        #pragma unroll
        for (int nb = 0; nb < 4; ++nb)
            #pragma unroll
            for (int r = 0; r < 4; ++r) o[nb][r] *= af[r];

        // ---- PV: O[q][d] += P·V
        const __bf16* V = Vlds[cur];
        __builtin_amdgcn_s_setprio(1);
        #pragma unroll
        for (int nb = 0; nb < 4; ++nb) {
            #pragma unroll
            for (int M = 0; M < 2; ++M) {
                bf16x8 vf = *(const bf16x8*)(V + ((((M << 2) + g) << 6) + (nb << 4) + c) * 8);
                o[nb] = __builtin_amdgcn_mfma_f32_16x16x32_bf16(pf[M], vf, o[nb], 0, 0, 0);
            }
        }
        __builtin_amdgcn_s_setprio(0);

        if (more) write_tile(cur ^ 1);  // ds_write next tile (waits its loads only)
        __syncthreads();                // single barrier per iter
        cur ^= 1;
    }

    // ---- epilogue: divide by row sum, store
    float linv[4];
    #pragma unroll
    for (int r = 0; r < 4; ++r) {
        float lr = __shfl(l_i, 4 * g + r);
        linv[r] = (lr > 0.f) ? 1.0f / lr : 0.f;
    }
    #pragma unroll
    for (int r = 0; r < 4; ++r) {
        int qrow = q0 + wid * 16 + 4 * g + r;
        if (qrow < len) {
            float* op = out + (((cu0 + qrow) * H_DIM + h) * D_DIM);
            #pragma unroll
            for (int nb = 0; nb < 4; ++nb)
                op[nb * 16 + c] = o[nb][r] * linv[r];
        }
    }
}

extern "C" void kernel_launch(void* const* d_in, const int* in_sizes, int n_in,
                              void* d_out, int out_size, void* d_ws, size_t ws_size,
                              hipStream_t stream) {
    const float* q  = (const float*)d_in[0];
    const float* k  = (const float*)d_in[1];
    const float* v  = (const float*)d_in[2];
    const int*   cu = (const int*)d_in[3];

    int nseq  = in_sizes[3] - 1;
    int T     = in_sizes[0] / (H_DIM * D_DIM);
    int S     = T / nseq;
    int tiles = (S + QBLK - 1) / QBLK;
    int nwg   = nseq * H_DIM * tiles;

    attn_fwd<<<nwg, NTHREADS, 0, stream>>>(q, k, v, cu, (float*)d_out, tiles);
}

// Round 3
// 61.264 us; speedup vs baseline: 2.5877x; 1.4341x over previous
//
#include <hip/hip_runtime.h>

#define H_DIM 16
#define D_DIM 64
#define QBLK 256
#define KVBLK 64
#define NTHREADS 512
#define TOKSTRIDE (H_DIM * D_DIM)   // floats per token

typedef __bf16 bf16x8 __attribute__((ext_vector_type(8)));
typedef float  f32x4  __attribute__((ext_vector_type(4)));

__global__ __launch_bounds__(NTHREADS, 4)
void attn_fwd(const float* __restrict__ qg, const float* __restrict__ kg,
              const float* __restrict__ vg, const int* __restrict__ cu,
              float* __restrict__ out, int tiles)
{
    __shared__ __align__(16) __bf16 Klds[2][KVBLK * D_DIM]; // XOR-swizzled row-major
    __shared__ __align__(16) __bf16 Vlds[2][KVBLK * D_DIM]; // PV-fragment order

    // XCD-bijective swizzle: all q-tiles/heads of one sequence on one XCD
    int nwg = gridDim.x;
    int bid = blockIdx.x;
    int lg = ((nwg & 7) == 0) ? ((bid & 7) * (nwg >> 3) + (bid >> 3)) : bid;

    int qt  = lg % tiles;
    int sh  = lg / tiles;
    int h   = sh % H_DIM;
    int seq = sh / H_DIM;

    int cu0 = cu[seq], cu1 = cu[seq + 1];
    int len = cu1 - cu0;
    int q0  = qt * QBLK;
    if (len <= 0 || q0 >= len) return;

    int tid  = threadIdx.x;
    int wid  = tid >> 6;    // 8 waves, each owns 32 q-rows (2 groups of 16)
    int lane = tid & 63;
    int g    = lane >> 4;
    int c    = lane & 15;

    const float SC = 0.125f * 1.44269504088896340736f; // 1/sqrt(D) * log2(e)

    // Q fragments: qf[rg][ks], lane holds Q[q0+wid*32+rg*16+c][32*ks + 8*g + i]
    bf16x8 qf[2][2];
    #pragma unroll
    for (int rg = 0; rg < 2; ++rg) {
        int qrow = q0 + wid * 32 + rg * 16 + c;
        bool valid = qrow < len;
        const float* qp = qg + ((cu0 + qrow) * TOKSTRIDE + h * D_DIM);
        #pragma unroll
        for (int ks = 0; ks < 2; ++ks) {
            float4 a = valid ? *(const float4*)(qp + ks * 32 + g * 8)     : make_float4(0,0,0,0);
            float4 b = valid ? *(const float4*)(qp + ks * 32 + g * 8 + 4) : make_float4(0,0,0,0);
            qf[rg][ks][0] = (__bf16)(a.x * SC); qf[rg][ks][1] = (__bf16)(a.y * SC);
            qf[rg][ks][2] = (__bf16)(a.z * SC); qf[rg][ks][3] = (__bf16)(a.w * SC);
            qf[rg][ks][4] = (__bf16)(b.x * SC); qf[rg][ks][5] = (__bf16)(b.y * SC);
            qf[rg][ks][6] = (__bf16)(b.z * SC); qf[rg][ks][7] = (__bf16)(b.w * SC);
        }
    }

    f32x4 o0[4] = {}, o1[4] = {};
    float m0 = -3.0e38f, m1 = -3.0e38f;
    float l0 = 0.0f,     l1 = 0.0f;

    // staging roles
    int krow = tid >> 3;
    int kc   = tid & 7;
    int kwoff = krow * 128 + ((kc * 16) ^ ((krow & 7) << 4));
    int vfg  = tid >> 6;
    int vd   = tid & 63;
    int vr0  = 32 * (vfg >> 2) + 4 * (vfg & 3);

    // running pointers (advance one KV tile per load)
    const float* kptr = kg + (cu0 + krow) * TOKSTRIDE + h * D_DIM + kc * 8;
    const float* vptr = vg + (cu0 + vr0)  * TOKSTRIDE + h * D_DIM + vd;

    float4 ka, kb;
    float  vv[8];

    auto load_fast = [&]() {
        ka = *(const float4*)kptr;
        kb = *(const float4*)(kptr + 4);
        #pragma unroll
        for (int i = 0; i < 8; ++i)
            vv[i] = vptr[(i >> 2) * (16 * TOKSTRIDE) + (i & 3) * TOKSTRIDE];
        kptr += KVBLK * TOKSTRIDE;
        vptr += KVBLK * TOKSTRIDE;
    };
    auto load_tail = [&](int kb0) {
        if (kb0 + krow < len) {
            ka = *(const float4*)kptr;
            kb = *(const float4*)(kptr + 4);
        } else {
            ka = make_float4(0,0,0,0); kb = make_float4(0,0,0,0);
        }
        #pragma unroll
        for (int i = 0; i < 8; ++i) {
            int r = kb0 + vr0 + 16 * (i >> 2) + (i & 3);
            vv[i] = (r < len) ? vptr[(i >> 2) * (16 * TOKSTRIDE) + (i & 3) * TOKSTRIDE] : 0.f;
        }
        kptr += KVBLK * TOKSTRIDE;
        vptr += KVBLK * TOKSTRIDE;
    };
    auto write_tile = [&](int buf) {
        bf16x8 kw;
        kw[0]=(__bf16)ka.x; kw[1]=(__bf16)ka.y; kw[2]=(__bf16)ka.z; kw[3]=(__bf16)ka.w;
        kw[4]=(__bf16)kb.x; kw[5]=(__bf16)kb.y; kw[6]=(__bf16)kb.z; kw[7]=(__bf16)kb.w;
        *(bf16x8*)((char*)Klds[buf] + kwoff) = kw;
        bf16x8 vw;
        #pragma unroll
        for (int i = 0; i < 8; ++i) vw[i] = (__bf16)vv[i];
        *(bf16x8*)(Vlds[buf] + (tid << 3)) = vw;
    };

    int nkv = (len + KVBLK - 1) / KVBLK;

    // prologue: stage tile 0
    if (KVBLK <= len) load_fast(); else load_tail(0);
    write_tile(0);
    __syncthreads();

    int cur = 0;
    for (int kt = 0; kt < nkv; ++kt) {
        int kbase = kt * KVBLK;
        bool more = kt + 1 < nkv;
        if (more) {
            int nb0 = kbase + KVBLK;
            if (nb0 + KVBLK <= len) load_fast(); else load_tail(nb0);
        }

        // ---- QK^T for both row-groups, K-frags shared
        const __bf16* K = Klds[cur];
        f32x4 s0[4] = {}, s1[4] = {};
        __builtin_amdgcn_s_setprio(1);
        #pragma unroll
        for (int b = 0; b < 4; ++b) {
            int rowk = 16 * b + c;
            int swz = (rowk & 7) << 4;
            const char* base = (const char*)K + rowk * 128;
            bf16x8 a0 = *(const bf16x8*)(base + ((16 * g)      ^ swz));
            bf16x8 a1 = *(const bf16x8*)(base + ((64 + 16 * g) ^ swz));
            s0[b] = __builtin_amdgcn_mfma_f32_16x16x32_bf16(a0, qf[0][0], s0[b], 0, 0, 0);
            s0[b] = __builtin_amdgcn_mfma_f32_16x16x32_bf16(a1, qf[0][1], s0[b], 0, 0, 0);
            s1[b] = __builtin_amdgcn_mfma_f32_16x16x32_bf16(a0, qf[1][0], s1[b], 0, 0, 0);
            s1[b] = __builtin_amdgcn_mfma_f32_16x16x32_bf16(a1, qf[1][1], s1[b], 0, 0, 0);
        }
        __builtin_amdgcn_s_setprio(0);

        // ---- varlen tail mask
        if (kbase + KVBLK > len) {
            #pragma unroll
            for (int b = 0; b < 4; ++b)
                #pragma unroll
                for (int r = 0; r < 4; ++r)
                    if (kbase + 16 * b + 4 * g + r >= len) { s0[b][r] = -3.0e38f; s1[b][r] = -3.0e38f; }
        }

        // ---- online softmax (log2 domain) with deferred rescale (T13)
        float t0 = fmaxf(fmaxf(fmaxf(s0[0][0],s0[0][1]),fmaxf(s0[0][2],s0[0][3])),
                         fmaxf(fmaxf(s0[1][0],s0[1][1]),fmaxf(s0[1][2],s0[1][3])));
        t0 = fmaxf(t0, fmaxf(fmaxf(fmaxf(s0[2][0],s0[2][1]),fmaxf(s0[2][2],s0[2][3])),
                             fmaxf(fmaxf(s0[3][0],s0[3][1]),fmaxf(s0[3][2],s0[3][3]))));
        float t1 = fmaxf(fmaxf(fmaxf(s1[0][0],s1[0][1]),fmaxf(s1[0][2],s1[0][3])),
                         fmaxf(fmaxf(s1[1][0],s1[1][1]),fmaxf(s1[1][2],s1[1][3])));
        t1 = fmaxf(t1, fmaxf(fmaxf(fmaxf(s1[2][0],s1[2][1]),fmaxf(s1[2][2],s1[2][3])),
                             fmaxf(fmaxf(s1[3][0],s1[3][1]),fmaxf(s1[3][2],s1[3][3]))));
        t0 = fmaxf(t0, __shfl_xor(t0, 16));
        t0 = fmaxf(t0, __shfl_xor(t0, 32));
        t1 = fmaxf(t1, __shfl_xor(t1, 16));
        t1 = fmaxf(t1, __shfl_xor(t1, 32));

        int ok = (t0 <= m0 + 8.f) && (t1 <= m1 + 8.f);
        if (!__all(ok)) {
            float mn0 = fmaxf(m0, t0), mn1 = fmaxf(m1, t1);
            float al0 = __builtin_amdgcn_exp2f(m0 - mn0);
            float al1 = __builtin_amdgcn_exp2f(m1 - mn1);
            m0 = mn0; m1 = mn1; l0 *= al0; l1 *= al1;
            #pragma unroll
            for (int r = 0; r < 4; ++r) {
                float a0f = __shfl(al0, 4 * g + r);
                float a1f = __shfl(al1, 4 * g + r);
                #pragma unroll
                for (int nb = 0; nb < 4; ++nb) { o0[nb][r] *= a0f; o1[nb][r] *= a1f; }
            }
        }

        // P fragments (kv = 32M + 16(i>>2) + 4g + (i&3)) + row sums
        bf16x8 p0[2], p1[2];
        float ps0 = 0.f, ps1 = 0.f;
        #pragma unroll
        for (int M = 0; M < 2; ++M)
            #pragma unroll
            for (int i = 0; i < 8; ++i) {
                float e0 = __builtin_amdgcn_exp2f(s0[2 * M + (i >> 2)][i & 3] - m0);
                float e1 = __builtin_amdgcn_exp2f(s1[2 * M + (i >> 2)][i & 3] - m1);
                p0[M][i] = (__bf16)e0; p1[M][i] = (__bf16)e1;
                ps0 += e0; ps1 += e1;
            }
        ps0 += __shfl_xor(ps0, 16); ps0 += __shfl_xor(ps0, 32);
        ps1 += __shfl_xor(ps1, 16); ps1 += __shfl_xor(ps1, 32);
        l0 += ps0; l1 += ps1;

        // ---- PV: V-frags shared between row-groups
        const __bf16* V = Vlds[cur];
        __builtin_amdgcn_s_setprio(1);
        #pragma unroll
        for (int nb = 0; nb < 4; ++nb) {
            #pragma unroll
            for (int M = 0; M < 2; ++M) {
                bf16x8 vf = *(const bf16x8*)(V + ((((M << 2) + g) << 6) + (nb << 4) + c) * 8);
                o0[nb] = __builtin_amdgcn_mfma_f32_16x16x32_bf16(p0[M], vf, o0[nb], 0, 0, 0);
                o1[nb] = __builtin_amdgcn_mfma_f32_16x16x32_bf16(p1[M], vf, o1[nb], 0, 0, 0);
            }
        }
        __builtin_amdgcn_s_setprio(0);

        if (more) write_tile(cur ^ 1);
        __syncthreads();
        cur ^= 1;
    }

    // ---- epilogue
    #pragma unroll
    for (int r = 0; r < 4; ++r) {
        float lr0 = __shfl(l0, 4 * g + r);
        float lr1 = __shfl(l1, 4 * g + r);
        float li0 = (lr0 > 0.f) ? 1.0f / lr0 : 0.f;
        float li1 = (lr1 > 0.f) ? 1.0f / lr1 : 0.f;
        int qrowA = q0 + wid * 32 + 4 * g + r;
        int qrowB = qrowA + 16;
        if (qrowA < len) {
            float* op = out + ((cu0 + qrowA) * TOKSTRIDE + h * D_DIM);
            #pragma unroll
            for (int nb = 0; nb < 4; ++nb) op[nb * 16 + c] = o0[nb][r] * li0;
        }
        if (qrowB < len) {
            float* op = out + ((cu0 + qrowB) * TOKSTRIDE + h * D_DIM);
            #pragma unroll
            for (int nb = 0; nb < 4; ++nb) op[nb * 16 + c] = o1[nb][r] * li1;
        }
    }
}

extern "C" void kernel_launch(void* const* d_in, const int* in_sizes, int n_in,
                              void* d_out, int out_size, void* d_ws, size_t ws_size,
                              hipStream_t stream) {
    const float* q  = (const float*)d_in[0];
    const float* k  = (const float*)d_in[1];
    const float* v  = (const float*)d_in[2];
    const int*   cu = (const int*)d_in[3];

    int nseq  = in_sizes[3] - 1;
    int T     = in_sizes[0] / (H_DIM * D_DIM);
    int S     = T / nseq;
    int tiles = (S + QBLK - 1) / QBLK;
    int nwg   = nseq * H_DIM * tiles;

    attn_fwd<<<nwg, NTHREADS, 0, stream>>>(q, k, v, cu, (float*)d_out, tiles);
}